// Round 2
// baseline (399.611 us; speedup 1.0000x reference)
//
#include <hip/hip_runtime.h>

// EquivariantGNN: B=8,S=32 -> 256 graphs, N=64 nodes, D=6, HID=64, all fp32.
// Kernel E: per-graph edge phase (h, a, c^T precompute; per-node T/M/U matmuls,
//           m_i via row-sum trick, pos_out). Kernel N: node MLP + vel_out.
// R1 fix: emb_w staging in edge kernel only covered 128/384 elements (tid-range
//         bug) -> h was garbage -> everything downstream wrong.

#define NGRAPH 256

__device__ __forceinline__ void fma4x4(float* acc, float4 a, float4 b){
  acc[0]  += a.x*b.x; acc[1]  += a.x*b.y; acc[2]  += a.x*b.z; acc[3]  += a.x*b.w;
  acc[4]  += a.y*b.x; acc[5]  += a.y*b.y; acc[6]  += a.y*b.z; acc[7]  += a.y*b.w;
  acc[8]  += a.z*b.x; acc[9]  += a.z*b.y; acc[10] += a.z*b.z; acc[11] += a.z*b.w;
  acc[12] += a.w*b.x; acc[13] += a.w*b.y; acc[14] += a.w*b.z; acc[15] += a.w*b.w;
}

__global__ __launch_bounds__(512)
void egnn_edge_kernel(const float* __restrict__ x,
    const float* __restrict__ emb_w,  const float* __restrict__ emb_b,
    const float* __restrict__ edge_w1,const float* __restrict__ edge_b1,
    const float* __restrict__ edge_w2,const float* __restrict__ edge_b2,
    const float* __restrict__ coord_w1,const float* __restrict__ coord_b1,
    const float* __restrict__ coord_w2,
    float* __restrict__ out, float* __restrict__ ws_mi)
{
  // big tiles (row strides 64 or padded 68 -> 16B aligned, conflict-free)
  __shared__ __align__(16) float sCT[64*68];   // c^T: [k][j], pad 68
  __shared__ __align__(16) float sA [64*64];   // a[i][k]
  __shared__ __align__(16) float sW2[64*64];   // stage W1a, then edge_w2 [k][n]
  __shared__ __align__(16) float sCW1[64*64];  // stage W1b, then coord_w1 [k][n]
  __shared__ __align__(16) float sT[2][64*64]; // T^T per group [k][j]
  __shared__ __align__(16) float sM[2][64*68]; // M^T per group [k][j], pad 68
  __shared__ __align__(16) float sHt[64*64];   // h^T [m][j] (phase A only)
  __shared__ float sXL[64*6];
  __shared__ float sEW[6*64];
  __shared__ float sEB[64], sB1[64], sB2[64], sCB1[64], sCW2[64], sW1L[64];
  __shared__ float sPX[64], sPY[64], sPZ[64];
  __shared__ float sDSQ[2][64], sTROW[2][64], sWJ[2][64];

  const int bs  = blockIdx.x;
  const int tid = threadIdx.x;
  const float* xg = x + bs*64*6;

  // ---- stage inputs (R1 fix: threads 0..383 stage BOTH x and emb_w) ----
  if (tid < 384){ sXL[tid] = xg[tid]; sEW[tid] = emb_w[tid]; }
  if (tid < 64){
    sEB[tid]  = emb_b[tid];    sB1[tid]  = edge_b1[tid];
    sB2[tid]  = edge_b2[tid];  sCB1[tid] = coord_b1[tid];
    sCW2[tid] = coord_w2[tid]; sW1L[tid] = edge_w1[128*64 + tid];
  } else if (tid < 128){
    int j = tid - 64;
    sPX[j] = xg[j*6+0]; sPY[j] = xg[j*6+1]; sPZ[j] = xg[j*6+2];
  }
  { // W1a (rows 0..63) -> sW2 buf, W1b (rows 64..127) -> sCW1 buf
    const float4* w1 = (const float4*)edge_w1;
    float4* d1 = (float4*)sW2; float4* d2 = (float4*)sCW1;
    #pragma unroll
    for (int e=0;e<2;e++){ int q = tid + e*512; d1[q] = w1[q]; d2[q] = w1[1024+q]; }
  }
  __syncthreads();

  // ---- h^T[m][j] ----
  #pragma unroll
  for (int e=0;e<8;e++){
    int idx = tid + e*512; int m = idx>>6, j = idx&63;
    float v = sEB[m];
    #pragma unroll
    for (int d=0; d<6; d++) v += sXL[j*6+d]*sEW[d*64+m];
    sHt[idx] = v;  // idx == m*64+j
  }
  __syncthreads();

  const int g  = tid >> 8;     // group (2 nodes concurrently)
  const int tl = tid & 255;
  const int tj = tl >> 4, tn = tl & 15;

  // ---- a = h@W1a (group 0), c^T from h@W1b (group 1) ----
  {
    float acc[16] = {};
    const float* Bm = g ? sCW1 : sW2;
    #pragma unroll 8
    for (int k=0;k<64;k++){
      float4 av = *(const float4*)&sHt[k*64 + 4*tj];
      float4 bv = *(const float4*)&Bm [k*64 + 4*tn];
      fma4x4(acc, av, bv);
    }
    if (g == 0){
      #pragma unroll
      for (int r=0;r<4;r++){
        float4 v = make_float4(acc[r*4+0],acc[r*4+1],acc[r*4+2],acc[r*4+3]);
        *(float4*)&sA[(4*tj+r)*64 + 4*tn] = v;
      }
    } else {
      #pragma unroll
      for (int c=0;c<4;c++){
        float4 v = make_float4(acc[0+c],acc[4+c],acc[8+c],acc[12+c]);
        *(float4*)&sCT[(4*tn+c)*68 + 4*tj] = v;
      }
    }
  }
  __syncthreads();
  { // overwrite with real edge_w2 / coord_w1
    const float4* w2g  = (const float4*)edge_w2;
    const float4* cw1g = (const float4*)coord_w1;
    float4* d1 = (float4*)sW2; float4* d2 = (float4*)sCW1;
    #pragma unroll
    for (int e=0;e<2;e++){ int q = tid + e*512; d1[q] = w2g[q]; d2[q] = cw1g[q]; }
  }
  __syncthreads();

  // ---- main per-node loop (2 nodes per iteration) ----
  for (int ib=0; ib<64; ib+=2){
    const int i = ib + g;
    if (tl < 64){
      int j = tl;
      float dx = sPX[i]-sPX[j], dy = sPY[i]-sPY[j], dz = sPZ[i]-sPZ[j];
      sDSQ[g][j] = dx*dx + dy*dy + dz*dz;
    }
    __syncthreads();

    // T^T fill + Trow (wave reduction; each (e,wave) owns one k)
    #pragma unroll
    for (int e=0;e<16;e++){
      int idx = tl + e*256; int k = idx>>6, j = idx&63;
      float v = sA[i*64+k] + sB1[k] + sCT[k*68+j] + sDSQ[g][j]*sW1L[k];
      v = fmaxf(v, 0.0f);
      sT[g][idx] = v;
      float s = v;
      #pragma unroll
      for (int off=1; off<64; off<<=1) s += __shfl_xor(s, off);
      if ((tid & 63) == 0) sTROW[g][k] = s;
    }
    __syncthreads();

    // matmul1: M = T@W2 + b2 -> sM (transposed, pad 68); m_i matvec
    {
      float acc[16] = {};
      #pragma unroll 8
      for (int k=0;k<64;k++){
        float4 av = *(const float4*)&sT[g][k*64 + 4*tj];
        float4 bv = *(const float4*)&sW2 [k*64 + 4*tn];
        fma4x4(acc, av, bv);
      }
      #pragma unroll
      for (int c=0;c<4;c++){
        float b2n = sB2[4*tn+c];
        float4 v = make_float4(acc[0+c]+b2n, acc[4+c]+b2n, acc[8+c]+b2n, acc[12+c]+b2n);
        *(float4*)&sM[g][(4*tn+c)*68 + 4*tj] = v;
      }
      if (tl < 64){
        int n = tl;
        float s = 64.0f * sB2[n];
        for (int k=0;k<64;k++) s += sTROW[g][k]*sW2[k*64+n];
        ws_mi[(bs*64 + i)*64 + n] = s;
      }
    }
    __syncthreads();

    // matmul2: U = relu(M@cw1 + cb1); w_j = U@cw2
    {
      float acc[16] = {};
      #pragma unroll 8
      for (int k=0;k<64;k++){
        float4 av = *(const float4*)&sM[g][k*68 + 4*tj];
        float4 bv = *(const float4*)&sCW1 [k*64 + 4*tn];
        fma4x4(acc, av, bv);
      }
      float p0=0.f,p1=0.f,p2=0.f,p3=0.f;
      #pragma unroll
      for (int c=0;c<4;c++){
        float cw = sCW2[4*tn+c], cb = sCB1[4*tn+c];
        p0 += fmaxf(acc[0+c]+cb, 0.f)*cw;
        p1 += fmaxf(acc[4+c]+cb, 0.f)*cw;
        p2 += fmaxf(acc[8+c]+cb, 0.f)*cw;
        p3 += fmaxf(acc[12+c]+cb, 0.f)*cw;
      }
      #pragma unroll
      for (int off=1; off<16; off<<=1){
        p0 += __shfl_xor(p0,off); p1 += __shfl_xor(p1,off);
        p2 += __shfl_xor(p2,off); p3 += __shfl_xor(p3,off);
      }
      if (tn == 0){
        sWJ[g][4*tj+0]=p0; sWJ[g][4*tj+1]=p1; sWJ[g][4*tj+2]=p2; sWJ[g][4*tj+3]=p3;
      }
    }
    __syncthreads();

    // pos accumulation
    if (tl < 64){
      int j = tl;
      float wj = sWJ[g][j];
      float cx = (sPX[i]-sPX[j])*wj;
      float cy = (sPY[i]-sPY[j])*wj;
      float cz = (sPZ[i]-sPZ[j])*wj;
      #pragma unroll
      for (int off=1; off<64; off<<=1){
        cx += __shfl_xor(cx,off); cy += __shfl_xor(cy,off); cz += __shfl_xor(cz,off);
      }
      if (j == 0){
        int base = (bs*64 + i)*6;
        out[base+0] = sPX[i] + cx*(1.0f/64.0f);
        out[base+1] = sPY[i] + cy*(1.0f/64.0f);
        out[base+2] = sPZ[i] + cz*(1.0f/64.0f);
      }
    }
  }
}

__global__ __launch_bounds__(256)
void egnn_node_kernel(const float* __restrict__ x,
    const float* __restrict__ emb_w,  const float* __restrict__ emb_b,
    const float* __restrict__ node_w1,const float* __restrict__ node_b1,
    const float* __restrict__ node_w2,const float* __restrict__ node_b2,
    const float* __restrict__ final_w,const float* __restrict__ final_b,
    float* __restrict__ out, const float* __restrict__ ws_mi)
{
  __shared__ __align__(16) float sHt [64*64];  // h^T [m][j]
  __shared__ __align__(16) float sMIt[64*68];  // m_i^T [n][i], pad 68
  __shared__ __align__(16) float sNW1[128*64];
  __shared__ __align__(16) float sNW2[64*64];
  __shared__ __align__(16) float sZt [64*68];  // z^T [k][j], pad 68
  __shared__ float sXL[384], sEW[384], sEB[64], sNB1[64], sNB2[64];
  __shared__ float sFW[64*3], sFB[3];

  const int bs = blockIdx.x, tid = threadIdx.x;
  const float* xg = x + bs*64*6;

  for (int q=tid; q<384; q+=256){ sXL[q]=xg[q]; sEW[q]=emb_w[q]; }
  if (tid < 64){ sEB[tid]=emb_b[tid]; sNB1[tid]=node_b1[tid]; sNB2[tid]=node_b2[tid]; }
  if (tid < 192) sFW[tid] = final_w[(tid/3)*6 + 3 + (tid%3)];
  if (tid < 3)   sFB[tid] = final_b[3+tid];
  {
    const float4* g1 = (const float4*)node_w1; float4* d1 = (float4*)sNW1;
    #pragma unroll
    for (int e=0;e<8;e++) d1[tid + e*256] = g1[tid + e*256];
    const float4* g2 = (const float4*)node_w2; float4* d2 = (float4*)sNW2;
    #pragma unroll
    for (int e=0;e<4;e++) d2[tid + e*256] = g2[tid + e*256];
  }
  const float* mig = ws_mi + bs*4096;
  #pragma unroll
  for (int e=0;e<16;e++){
    int idx = tid + e*256; int iN = idx>>6, n = idx&63;
    sMIt[n*68 + iN] = mig[idx];
  }
  __syncthreads();
  #pragma unroll
  for (int e=0;e<16;e++){
    int idx = tid + e*256; int m = idx>>6, j = idx&63;
    float v = sEB[m];
    #pragma unroll
    for (int d=0;d<6;d++) v += sXL[j*6+d]*sEW[d*64+m];
    sHt[idx] = v;
  }
  __syncthreads();

  const int tj = tid>>4, tn = tid&15;
  // z = relu([h, m_i] @ nw1 + nb1)  (K=128)
  {
    float acc[16] = {};
    #pragma unroll 8
    for (int k=0;k<64;k++){
      float4 av = *(const float4*)&sHt [k*64 + 4*tj];
      float4 bv = *(const float4*)&sNW1[k*64 + 4*tn];
      fma4x4(acc, av, bv);
    }
    #pragma unroll 8
    for (int k=0;k<64;k++){
      float4 av = *(const float4*)&sMIt[k*68 + 4*tj];
      float4 bv = *(const float4*)&sNW1[(64+k)*64 + 4*tn];
      fma4x4(acc, av, bv);
    }
    #pragma unroll
    for (int c=0;c<4;c++){
      float nb = sNB1[4*tn+c];
      float4 v = make_float4(fmaxf(acc[0+c]+nb,0.f), fmaxf(acc[4+c]+nb,0.f),
                             fmaxf(acc[8+c]+nb,0.f), fmaxf(acc[12+c]+nb,0.f));
      *(float4*)&sZt[(4*tn+c)*68 + 4*tj] = v;
    }
  }
  __syncthreads();
  // h_new = h + z@nw2 + nb2 ; vel_out = vel + h_new@fw[:,3:6] + fb[3:6]
  {
    float acc[16] = {};
    #pragma unroll 8
    for (int k=0;k<64;k++){
      float4 av = *(const float4*)&sZt [k*68 + 4*tj];
      float4 bv = *(const float4*)&sNW2[k*64 + 4*tn];
      fma4x4(acc, av, bv);
    }
    float fv[4][3] = {};
    #pragma unroll
    for (int r=0;r<4;r++){
      #pragma unroll
      for (int c=0;c<4;c++){
        int n = 4*tn+c, j = 4*tj+r;
        float hn = acc[r*4+c] + sHt[n*64 + j] + sNB2[n];
        fv[r][0] += hn*sFW[n*3+0];
        fv[r][1] += hn*sFW[n*3+1];
        fv[r][2] += hn*sFW[n*3+2];
      }
    }
    #pragma unroll
    for (int off=1; off<16; off<<=1){
      #pragma unroll
      for (int r=0;r<4;r++){
        fv[r][0] += __shfl_xor(fv[r][0], off);
        fv[r][1] += __shfl_xor(fv[r][1], off);
        fv[r][2] += __shfl_xor(fv[r][2], off);
      }
    }
    if (tn == 0){
      #pragma unroll
      for (int r=0;r<4;r++){
        int j = 4*tj+r; int base = (bs*64+j)*6;
        #pragma unroll
        for (int d=0;d<3;d++)
          out[base+3+d] = xg[j*6+3+d] + sFB[d] + fv[r][d];
      }
    }
  }
}

extern "C" void kernel_launch(void* const* d_in, const int* in_sizes, int n_in,
                              void* d_out, int out_size, void* d_ws, size_t ws_size,
                              hipStream_t stream)
{
  const float* x        = (const float*)d_in[0];
  const float* emb_w    = (const float*)d_in[1];
  const float* emb_b    = (const float*)d_in[2];
  const float* edge_w1  = (const float*)d_in[3];
  const float* edge_b1  = (const float*)d_in[4];
  const float* edge_w2  = (const float*)d_in[5];
  const float* edge_b2  = (const float*)d_in[6];
  const float* node_w1  = (const float*)d_in[7];
  const float* node_b1  = (const float*)d_in[8];
  const float* node_w2  = (const float*)d_in[9];
  const float* node_b2  = (const float*)d_in[10];
  const float* coord_w1 = (const float*)d_in[11];
  const float* coord_b1 = (const float*)d_in[12];
  const float* coord_w2 = (const float*)d_in[13];
  const float* final_w  = (const float*)d_in[14];
  const float* final_b  = (const float*)d_in[15];
  float* out   = (float*)d_out;
  float* ws_mi = (float*)d_ws;   // 256*64*64 floats = 4 MB

  egnn_edge_kernel<<<NGRAPH, 512, 0, stream>>>(x, emb_w, emb_b,
      edge_w1, edge_b1, edge_w2, edge_b2, coord_w1, coord_b1, coord_w2,
      out, ws_mi);
  egnn_node_kernel<<<NGRAPH, 256, 0, stream>>>(x, emb_w, emb_b,
      node_w1, node_b1, node_w2, node_b2, final_w, final_b,
      out, ws_mi);
}

// Round 3
// 133.376 us; speedup vs baseline: 2.9961x; 2.9961x over previous
//
#include <hip/hip_runtime.h>

// EquivariantGNN: 256 graphs, N=64 nodes, HID=64, fp32 in/out.
// R3: edge kernel rewritten around bf16 MFMA (16x16x32) with two algebraic
// eliminations: W3=W2@cw1 folds away the M GEMM (relu only after cw1-add),
// and m_i = Trow@W2 + 64*b2 (row-sum) becomes one batched GEMM per graph.
// Main loop is barrier-free: each of 8 waves owns its own node i.

#define NG 256

typedef __attribute__((ext_vector_type(4))) float f32x4;
typedef __attribute__((ext_vector_type(8))) __bf16 bf16x8;

__device__ __forceinline__ f32x4 mfma16(bf16x8 a, bf16x8 b, f32x4 c){
  return __builtin_amdgcn_mfma_f32_16x16x32_bf16(a, b, c, 0, 0, 0);
}

__device__ __forceinline__ void fma4x4(float* acc, float4 a, float4 b){
  acc[0]  += a.x*b.x; acc[1]  += a.x*b.y; acc[2]  += a.x*b.z; acc[3]  += a.x*b.w;
  acc[4]  += a.y*b.x; acc[5]  += a.y*b.y; acc[6]  += a.y*b.z; acc[7]  += a.y*b.w;
  acc[8]  += a.z*b.x; acc[9]  += a.z*b.y; acc[10] += a.z*b.z; acc[11] += a.z*b.w;
  acc[12] += a.w*b.x; acc[13] += a.w*b.y; acc[14] += a.w*b.z; acc[15] += a.w*b.w;
}

__global__ __launch_bounds__(512, 2)
void egnn_edge_mfma(const float* __restrict__ x,
    const float* __restrict__ emb_w,  const float* __restrict__ emb_b,
    const float* __restrict__ edge_w1,const float* __restrict__ edge_b1,
    const float* __restrict__ edge_w2,const float* __restrict__ edge_b2,
    const float* __restrict__ coord_w1,const float* __restrict__ coord_b1,
    const float* __restrict__ coord_w2,
    float* __restrict__ out, float* __restrict__ ws_mi)
{
  // persistent (main loop)
  __shared__ __align__(16) float  sAB [64*64];   // a_i[k]+b1[k], f32 [i][k]
  __shared__ __align__(16) __bf16 sC  [64*72];   // c_j[k] bf16 [j][72]
  __shared__ __align__(16) __bf16 sW3t[64*72];   // (W2@cw1)^T [n'][k]
  __shared__ __align__(16) __bf16 sW2t[64*72];   // W2^T [n][k]
  __shared__ __align__(16) __bf16 sTr [64*72];   // Trow [i][k]
  __shared__ float sDsq[8][64];
  __shared__ float sPX[64], sPY[64], sPZ[64];
  __shared__ __align__(16) float sW1L[64];
  __shared__ float sCB1p[64], sCW2[64], sB2[64], sB1[64];
  // precompute scratch
  __shared__ __align__(16) float sW1a[64*64], sW1b[64*64], sW2T[64*64], sCW1[64*64];
  __shared__ __align__(16) float sHt[64*64];
  __shared__ float sXL[384], sEW[384], sEB[64];

  const int bs  = blockIdx.x, tid = threadIdx.x;
  const int lane = tid & 63, wv = tid >> 6;
  const float* xg = x + bs*384;

  // ---- stage ----
  if (tid < 384){ sXL[tid] = xg[tid]; sEW[tid] = emb_w[tid]; }
  if (tid < 64){
    sEB[tid] = emb_b[tid];  sB1[tid] = edge_b1[tid]; sB2[tid] = edge_b2[tid];
    sCW2[tid] = coord_w2[tid]; sW1L[tid] = edge_w1[128*64 + tid];
  } else if (tid < 128){
    int j = tid-64; sPX[j]=xg[j*6]; sPY[j]=xg[j*6+1]; sPZ[j]=xg[j*6+2];
  }
  {
    const float4* w1 = (const float4*)edge_w1;
    const float4* cw = (const float4*)coord_w1;
    float4* da=(float4*)sW1a; float4* db=(float4*)sW1b; float4* dc=(float4*)sCW1;
    #pragma unroll
    for (int e=0;e<2;e++){ int q=tid+e*512; da[q]=w1[q]; db[q]=w1[1024+q]; dc[q]=cw[q]; }
  }
  // W2 transposed into LDS: thread owns (n,k) -> contiguous LDS writes
  #pragma unroll
  for (int e=0;e<8;e++){ int idx=tid+e*512; int n=idx>>6, k=idx&63;
    sW2T[idx] = edge_w2[k*64+n]; }   // sW2T[n*64+k] = W2[k][n]
  __syncthreads();

  // ---- h^T[m][j] (fp32) ----
  #pragma unroll
  for (int e=0;e<8;e++){
    int idx=tid+e*512; int m=idx>>6, j=idx&63;
    float v = sEB[m];
    #pragma unroll
    for (int d=0;d<6;d++) v += sXL[j*6+d]*sEW[d*64+m];
    sHt[idx] = v;
  }
  __syncthreads();

  const int g = tid>>8, tl = tid&255, tjx = tl>>4, tnx = tl&15;
  // group0: ab = h@W1a + b1 (fp32) ; group1: c = h@W1b (bf16)
  {
    float acc[16] = {};
    const float* Bm = g ? sW1b : sW1a;
    #pragma unroll 8
    for (int k=0;k<64;k++){
      float4 av = *(const float4*)&sHt[k*64 + 4*tjx];
      float4 bv = *(const float4*)&Bm [k*64 + 4*tnx];
      fma4x4(acc, av, bv);
    }
    if (g==0){
      #pragma unroll
      for (int r=0;r<4;r++)
        #pragma unroll
        for (int c=0;c<4;c++)
          sAB[(4*tjx+r)*64 + 4*tnx+c] = acc[r*4+c] + sB1[4*tnx+c];
    } else {
      #pragma unroll
      for (int r=0;r<4;r++)
        #pragma unroll
        for (int c=0;c<4;c++)
          sC[(4*tjx+r)*72 + 4*tnx+c] = (__bf16)acc[r*4+c];
    }
  }
  // group0: W3 = W2@cw1 -> sW3t bf16 ; group1: W2t bf16 + cb1' = cb1 + b2@cw1
  if (g==0){
    float acc[16] = {};
    #pragma unroll 8
    for (int k=0;k<64;k++){
      float4 av = *(const float4*)&sW2T[k*64 + 4*tjx];  // W2[4tjx+r][k]
      float4 bv = *(const float4*)&sCW1[k*64 + 4*tnx];  // cw1[k][4tnx+c]
      fma4x4(acc, av, bv);
    }
    #pragma unroll
    for (int r=0;r<4;r++)
      #pragma unroll
      for (int c=0;c<4;c++)
        sW3t[(4*tnx+c)*72 + 4*tjx+r] = (__bf16)acc[r*4+c];
  } else {
    #pragma unroll
    for (int e=0;e<16;e++){ int idx=tl+e*256; sW2t[(idx>>6)*72 + (idx&63)] = (__bf16)sW2T[idx]; }
    if (tl < 64){
      float s = coord_b1[tl];
      for (int n=0;n<64;n++) s += sB2[n]*sCW1[n*64+tl];
      sCB1p[tl] = s;
    }
  }
  __syncthreads();

  const int lg = lane>>4, ln = lane&15;   // k-slot group / tile row-col

  // resident B-fragments of W3^T (invariant over i)
  bf16x8 bW3[4][2];
  #pragma unroll
  for (int nt=0;nt<4;nt++)
    #pragma unroll
    for (int kb=0;kb<2;kb++)
      bW3[nt][kb] = *(const bf16x8*)&sW3t[(nt*16+ln)*72 + kb*32 + lg*8];

  // ---- main loop: wave wv owns node i = ib*8+wv; NO barriers ----
  for (int ib=0; ib<8; ib++){
    const int i = ib*8 + wv;
    {
      float dx=sPX[i]-sPX[lane], dy=sPY[i]-sPY[lane], dz=sPZ[i]-sPZ[lane];
      sDsq[wv][lane] = dx*dx+dy*dy+dz*dz;
    }
    f32x4 acc[4][4];
    #pragma unroll
    for (int a=0;a<4;a++)
      #pragma unroll
      for (int b=0;b<4;b++) acc[a][b] = f32x4{0.f,0.f,0.f,0.f};
    float trs[2][8];
    #pragma unroll
    for (int kb=0;kb<2;kb++)
      #pragma unroll
      for (int e=0;e<8;e++) trs[kb][e]=0.f;

    #pragma unroll
    for (int kb=0;kb<2;kb++){
      const int k0 = kb*32 + lg*8;
      float ab8[8], w18[8];
      *(float4*)&ab8[0] = *(const float4*)&sAB[i*64+k0];
      *(float4*)&ab8[4] = *(const float4*)&sAB[i*64+k0+4];
      *(float4*)&w18[0] = *(const float4*)&sW1L[k0];
      *(float4*)&w18[4] = *(const float4*)&sW1L[k0+4];
      bf16x8 af[4];
      #pragma unroll
      for (int jt=0;jt<4;jt++){
        int j = jt*16 + ln;
        float dq = sDsq[wv][j];
        bf16x8 c8 = *(const bf16x8*)&sC[j*72 + k0];
        bf16x8 t8;
        #pragma unroll
        for (int e=0;e<8;e++){
          float v = ab8[e] + (float)c8[e] + dq*w18[e];
          v = fmaxf(v, 0.f);
          trs[kb][e] += v;
          t8[e] = (__bf16)v;
        }
        af[jt] = t8;
      }
      #pragma unroll
      for (int jt=0;jt<4;jt++)
        #pragma unroll
        for (int nt=0;nt<4;nt++)
          acc[jt][nt] = mfma16(af[jt], bW3[nt][kb], acc[jt][nt]);
    }

    // Trow: butterfly over the 16 j-lanes, then 4 lanes store bf16x8
    #pragma unroll
    for (int kb=0;kb<2;kb++)
      #pragma unroll
      for (int e=0;e<8;e++){
        float s = trs[kb][e];
        s += __shfl_xor(s,1); s += __shfl_xor(s,2);
        s += __shfl_xor(s,4); s += __shfl_xor(s,8);
        trs[kb][e] = s;
      }
    if (ln == 0){
      #pragma unroll
      for (int kb=0;kb<2;kb++){
        bf16x8 t8;
        #pragma unroll
        for (int e=0;e<8;e++) t8[e] = (__bf16)trs[kb][e];
        *(bf16x8*)&sTr[i*72 + kb*32 + lg*8] = t8;
      }
    }

    // epilogue: w_j = relu(U+cb1')·cw2 ; pos_out
    float sw=0.f, swx=0.f, swy=0.f, swz=0.f;
    #pragma unroll
    for (int jt=0;jt<4;jt++){
      float wr[4];
      #pragma unroll
      for (int r=0;r<4;r++){
        float p = 0.f;
        #pragma unroll
        for (int nt=0;nt<4;nt++){
          int n = nt*16 + ln;
          float u = acc[jt][nt][r] + sCB1p[n];
          p += fmaxf(u, 0.f)*sCW2[n];
        }
        p += __shfl_xor(p,1); p += __shfl_xor(p,2);
        p += __shfl_xor(p,4); p += __shfl_xor(p,8);
        wr[r] = p;
      }
      #pragma unroll
      for (int r=0;r<4;r++){
        int j = jt*16 + lg*4 + r;
        sw  += wr[r];
        swx += wr[r]*sPX[j];
        swy += wr[r]*sPY[j];
        swz += wr[r]*sPZ[j];
      }
    }
    sw  += __shfl_xor(sw,16);  sw  += __shfl_xor(sw,32);
    swx += __shfl_xor(swx,16); swx += __shfl_xor(swx,32);
    swy += __shfl_xor(swy,16); swy += __shfl_xor(swy,32);
    swz += __shfl_xor(swz,16); swz += __shfl_xor(swz,32);
    if (lane == 0){
      float* o = out + (bs*64 + i)*6;
      o[0] = sPX[i] + (sPX[i]*sw - swx)*(1.f/64.f);
      o[1] = sPY[i] + (sPY[i]*sw - swy)*(1.f/64.f);
      o[2] = sPZ[i] + (sPZ[i]*sw - swz)*(1.f/64.f);
    }
  }

  // ---- batched m_i = Trow@W2 + 64*b2 (one GEMM for all 64 i) ----
  __syncthreads();
  #pragma unroll
  for (int t2=0;t2<2;t2++){
    int t  = wv*2 + t2;
    int it = t>>2, nt = t&3;
    f32x4 a2 = f32x4{0.f,0.f,0.f,0.f};
    #pragma unroll
    for (int kb=0;kb<2;kb++){
      bf16x8 a8 = *(const bf16x8*)&sTr [(it*16+ln)*72 + kb*32 + lg*8];
      bf16x8 b8 = *(const bf16x8*)&sW2t[(nt*16+ln)*72 + kb*32 + lg*8];
      a2 = mfma16(a8, b8, a2);
    }
    int n = nt*16 + ln;
    float b2n = 64.f*sB2[n];
    #pragma unroll
    for (int r=0;r<4;r++){
      int i = it*16 + lg*4 + r;
      ws_mi[(bs*64 + i)*64 + n] = a2[r] + b2n;
    }
  }
}

__global__ __launch_bounds__(256)
void egnn_node_kernel(const float* __restrict__ x,
    const float* __restrict__ emb_w,  const float* __restrict__ emb_b,
    const float* __restrict__ node_w1,const float* __restrict__ node_b1,
    const float* __restrict__ node_w2,const float* __restrict__ node_b2,
    const float* __restrict__ final_w,const float* __restrict__ final_b,
    float* __restrict__ out, const float* __restrict__ ws_mi)
{
  __shared__ __align__(16) float sHt [64*64];  // h^T [m][j]
  __shared__ __align__(16) float sMIt[64*68];  // m_i^T [n][i], pad 68
  __shared__ __align__(16) float sNW1[128*64];
  __shared__ __align__(16) float sNW2[64*64];
  __shared__ __align__(16) float sZt [64*68];  // z^T [k][j], pad 68
  __shared__ float sXL[384], sEW[384], sEB[64], sNB1[64], sNB2[64];
  __shared__ float sFW[64*3], sFB[3];

  const int bs = blockIdx.x, tid = threadIdx.x;
  const float* xg = x + bs*64*6;

  for (int q=tid; q<384; q+=256){ sXL[q]=xg[q]; sEW[q]=emb_w[q]; }
  if (tid < 64){ sEB[tid]=emb_b[tid]; sNB1[tid]=node_b1[tid]; sNB2[tid]=node_b2[tid]; }
  if (tid < 192) sFW[tid] = final_w[(tid/3)*6 + 3 + (tid%3)];
  if (tid < 3)   sFB[tid] = final_b[3+tid];
  {
    const float4* g1 = (const float4*)node_w1; float4* d1 = (float4*)sNW1;
    #pragma unroll
    for (int e=0;e<8;e++) d1[tid + e*256] = g1[tid + e*256];
    const float4* g2 = (const float4*)node_w2; float4* d2 = (float4*)sNW2;
    #pragma unroll
    for (int e=0;e<4;e++) d2[tid + e*256] = g2[tid + e*256];
  }
  const float* mig = ws_mi + bs*4096;
  #pragma unroll
  for (int e=0;e<16;e++){
    int idx = tid + e*256; int iN = idx>>6, n = idx&63;
    sMIt[n*68 + iN] = mig[idx];
  }
  __syncthreads();
  #pragma unroll
  for (int e=0;e<16;e++){
    int idx = tid + e*256; int m = idx>>6, j = idx&63;
    float v = sEB[m];
    #pragma unroll
    for (int d=0;d<6;d++) v += sXL[j*6+d]*sEW[d*64+m];
    sHt[idx] = v;
  }
  __syncthreads();

  const int tj = tid>>4, tn = tid&15;
  {
    float acc[16] = {};
    #pragma unroll 8
    for (int k=0;k<64;k++){
      float4 av = *(const float4*)&sHt [k*64 + 4*tj];
      float4 bv = *(const float4*)&sNW1[k*64 + 4*tn];
      fma4x4(acc, av, bv);
    }
    #pragma unroll 8
    for (int k=0;k<64;k++){
      float4 av = *(const float4*)&sMIt[k*68 + 4*tj];
      float4 bv = *(const float4*)&sNW1[(64+k)*64 + 4*tn];
      fma4x4(acc, av, bv);
    }
    #pragma unroll
    for (int c=0;c<4;c++){
      float nb = sNB1[4*tn+c];
      float4 v = make_float4(fmaxf(acc[0+c]+nb,0.f), fmaxf(acc[4+c]+nb,0.f),
                             fmaxf(acc[8+c]+nb,0.f), fmaxf(acc[12+c]+nb,0.f));
      *(float4*)&sZt[(4*tn+c)*68 + 4*tj] = v;
    }
  }
  __syncthreads();
  {
    float acc[16] = {};
    #pragma unroll 8
    for (int k=0;k<64;k++){
      float4 av = *(const float4*)&sZt [k*68 + 4*tj];
      float4 bv = *(const float4*)&sNW2[k*64 + 4*tn];
      fma4x4(acc, av, bv);
    }
    float fv[4][3] = {};
    #pragma unroll
    for (int r=0;r<4;r++){
      #pragma unroll
      for (int c=0;c<4;c++){
        int n = 4*tn+c, j = 4*tj+r;
        float hn = acc[r*4+c] + sHt[n*64 + j] + sNB2[n];
        fv[r][0] += hn*sFW[n*3+0];
        fv[r][1] += hn*sFW[n*3+1];
        fv[r][2] += hn*sFW[n*3+2];
      }
    }
    #pragma unroll
    for (int off=1; off<16; off<<=1){
      #pragma unroll
      for (int r=0;r<4;r++){
        fv[r][0] += __shfl_xor(fv[r][0], off);
        fv[r][1] += __shfl_xor(fv[r][1], off);
        fv[r][2] += __shfl_xor(fv[r][2], off);
      }
    }
    if (tn == 0){
      #pragma unroll
      for (int r=0;r<4;r++){
        int j = 4*tj+r; int base = (bs*64+j)*6;
        #pragma unroll
        for (int d=0;d<3;d++)
          out[base+3+d] = xg[j*6+3+d] + sFB[d] + fv[r][d];
      }
    }
  }
}

extern "C" void kernel_launch(void* const* d_in, const int* in_sizes, int n_in,
                              void* d_out, int out_size, void* d_ws, size_t ws_size,
                              hipStream_t stream)
{
  const float* x        = (const float*)d_in[0];
  const float* emb_w    = (const float*)d_in[1];
  const float* emb_b    = (const float*)d_in[2];
  const float* edge_w1  = (const float*)d_in[3];
  const float* edge_b1  = (const float*)d_in[4];
  const float* edge_w2  = (const float*)d_in[5];
  const float* edge_b2  = (const float*)d_in[6];
  const float* node_w1  = (const float*)d_in[7];
  const float* node_b1  = (const float*)d_in[8];
  const float* node_w2  = (const float*)d_in[9];
  const float* node_b2  = (const float*)d_in[10];
  const float* coord_w1 = (const float*)d_in[11];
  const float* coord_b1 = (const float*)d_in[12];
  const float* coord_w2 = (const float*)d_in[13];
  const float* final_w  = (const float*)d_in[14];
  const float* final_b  = (const float*)d_in[15];
  float* out   = (float*)d_out;
  float* ws_mi = (float*)d_ws;   // 256*64*64 f32 = 4 MB

  egnn_edge_mfma<<<NG, 512, 0, stream>>>(x, emb_w, emb_b,
      edge_w1, edge_b1, edge_w2, edge_b2, coord_w1, coord_b1, coord_w2,
      out, ws_mi);
  egnn_node_kernel<<<NG, 256, 0, stream>>>(x, emb_w, emb_b,
      node_w1, node_b1, node_w2, node_b2, final_w, final_b,
      out, ws_mi);
}

// Round 4
// 86.947 us; speedup vs baseline: 4.5960x; 1.5340x over previous
//
#include <hip/hip_runtime.h>

// EquivariantGNN: 256 graphs, N=64 nodes, HID=64, fp32 in/out.
// R4: fix register spill (R3: FETCH 75MB/WRITE 42MB scratch traffic).
//  - jt-outer main loop: only 4 f32x4 accumulators live (was 16).
//  - __launch_bounds__(512,1): LDS already caps at 1 block/CU; allow 256 VGPRs.

#define NG 256

typedef __attribute__((ext_vector_type(4))) float f32x4;
typedef __attribute__((ext_vector_type(8))) __bf16 bf16x8;

__device__ __forceinline__ f32x4 mfma16(bf16x8 a, bf16x8 b, f32x4 c){
  return __builtin_amdgcn_mfma_f32_16x16x32_bf16(a, b, c, 0, 0, 0);
}

__device__ __forceinline__ void fma4x4(float* acc, float4 a, float4 b){
  acc[0]  += a.x*b.x; acc[1]  += a.x*b.y; acc[2]  += a.x*b.z; acc[3]  += a.x*b.w;
  acc[4]  += a.y*b.x; acc[5]  += a.y*b.y; acc[6]  += a.y*b.z; acc[7]  += a.y*b.w;
  acc[8]  += a.z*b.x; acc[9]  += a.z*b.y; acc[10] += a.z*b.z; acc[11] += a.z*b.w;
  acc[12] += a.w*b.x; acc[13] += a.w*b.y; acc[14] += a.w*b.z; acc[15] += a.w*b.w;
}

__global__ __launch_bounds__(512, 1)
void egnn_edge_mfma(const float* __restrict__ x,
    const float* __restrict__ emb_w,  const float* __restrict__ emb_b,
    const float* __restrict__ edge_w1,const float* __restrict__ edge_b1,
    const float* __restrict__ edge_w2,const float* __restrict__ edge_b2,
    const float* __restrict__ coord_w1,const float* __restrict__ coord_b1,
    const float* __restrict__ coord_w2,
    float* __restrict__ out, float* __restrict__ ws_mi)
{
  // persistent (main loop)
  __shared__ __align__(16) float  sAB [64*64];   // a_i[k]+b1[k], f32 [i][k]
  __shared__ __align__(16) __bf16 sC  [64*72];   // c_j[k] bf16 [j][72]
  __shared__ __align__(16) __bf16 sW3t[64*72];   // (W2@cw1)^T [n'][k]
  __shared__ __align__(16) __bf16 sW2t[64*72];   // W2^T [n][k]
  __shared__ __align__(16) __bf16 sTr [64*72];   // Trow [i][k]
  __shared__ float sDsq[8][64];
  __shared__ float sPX[64], sPY[64], sPZ[64];
  __shared__ __align__(16) float sW1L[64];
  __shared__ float sCB1p[64], sCW2[64], sB2[64], sB1[64];
  // precompute scratch
  __shared__ __align__(16) float sW1a[64*64], sW1b[64*64], sW2T[64*64], sCW1[64*64];
  __shared__ __align__(16) float sHt[64*64];
  __shared__ float sXL[384], sEW[384], sEB[64];

  const int bs  = blockIdx.x, tid = threadIdx.x;
  const int lane = tid & 63, wv = tid >> 6;
  const float* xg = x + bs*384;

  // ---- stage ----
  if (tid < 384){ sXL[tid] = xg[tid]; sEW[tid] = emb_w[tid]; }
  if (tid < 64){
    sEB[tid] = emb_b[tid];  sB1[tid] = edge_b1[tid]; sB2[tid] = edge_b2[tid];
    sCW2[tid] = coord_w2[tid]; sW1L[tid] = edge_w1[128*64 + tid];
  } else if (tid < 128){
    int j = tid-64; sPX[j]=xg[j*6]; sPY[j]=xg[j*6+1]; sPZ[j]=xg[j*6+2];
  }
  {
    const float4* w1 = (const float4*)edge_w1;
    const float4* cw = (const float4*)coord_w1;
    float4* da=(float4*)sW1a; float4* db=(float4*)sW1b; float4* dc=(float4*)sCW1;
    #pragma unroll
    for (int e=0;e<2;e++){ int q=tid+e*512; da[q]=w1[q]; db[q]=w1[1024+q]; dc[q]=cw[q]; }
  }
  // W2 transposed into LDS
  #pragma unroll
  for (int e=0;e<8;e++){ int idx=tid+e*512; int n=idx>>6, k=idx&63;
    sW2T[idx] = edge_w2[k*64+n]; }   // sW2T[n*64+k] = W2[k][n]
  __syncthreads();

  // ---- h^T[m][j] (fp32) ----
  #pragma unroll
  for (int e=0;e<8;e++){
    int idx=tid+e*512; int m=idx>>6, j=idx&63;
    float v = sEB[m];
    #pragma unroll
    for (int d=0;d<6;d++) v += sXL[j*6+d]*sEW[d*64+m];
    sHt[idx] = v;
  }
  __syncthreads();

  const int g = tid>>8, tl = tid&255, tjx = tl>>4, tnx = tl&15;
  // group0: ab = h@W1a + b1 (fp32) ; group1: c = h@W1b (bf16)
  {
    float acc[16] = {};
    const float* Bm = g ? sW1b : sW1a;
    #pragma unroll 8
    for (int k=0;k<64;k++){
      float4 av = *(const float4*)&sHt[k*64 + 4*tjx];
      float4 bv = *(const float4*)&Bm [k*64 + 4*tnx];
      fma4x4(acc, av, bv);
    }
    if (g==0){
      #pragma unroll
      for (int r=0;r<4;r++)
        #pragma unroll
        for (int c=0;c<4;c++)
          sAB[(4*tjx+r)*64 + 4*tnx+c] = acc[r*4+c] + sB1[4*tnx+c];
    } else {
      #pragma unroll
      for (int r=0;r<4;r++)
        #pragma unroll
        for (int c=0;c<4;c++)
          sC[(4*tjx+r)*72 + 4*tnx+c] = (__bf16)acc[r*4+c];
    }
  }
  // group0: W3 = W2@cw1 -> sW3t bf16 ; group1: W2t bf16 + cb1' = cb1 + b2@cw1
  if (g==0){
    float acc[16] = {};
    #pragma unroll 8
    for (int k=0;k<64;k++){
      float4 av = *(const float4*)&sW2T[k*64 + 4*tjx];
      float4 bv = *(const float4*)&sCW1[k*64 + 4*tnx];
      fma4x4(acc, av, bv);
    }
    #pragma unroll
    for (int r=0;r<4;r++)
      #pragma unroll
      for (int c=0;c<4;c++)
        sW3t[(4*tnx+c)*72 + 4*tjx+r] = (__bf16)acc[r*4+c];
  } else {
    #pragma unroll
    for (int e=0;e<16;e++){ int idx=tl+e*256; sW2t[(idx>>6)*72 + (idx&63)] = (__bf16)sW2T[idx]; }
    if (tl < 64){
      float s = coord_b1[tl];
      for (int n=0;n<64;n++) s += sB2[n]*sCW1[n*64+tl];
      sCB1p[tl] = s;
    }
  }
  __syncthreads();

  const int lg = lane>>4, ln = lane&15;

  // invariants hoisted into registers
  bf16x8 bW3[4][2];
  #pragma unroll
  for (int nt=0;nt<4;nt++)
    #pragma unroll
    for (int kb=0;kb<2;kb++)
      bW3[nt][kb] = *(const bf16x8*)&sW3t[(nt*16+ln)*72 + kb*32 + lg*8];
  float w18[2][8];
  #pragma unroll
  for (int kb=0;kb<2;kb++){
    *(float4*)&w18[kb][0] = *(const float4*)&sW1L[kb*32+lg*8];
    *(float4*)&w18[kb][4] = *(const float4*)&sW1L[kb*32+lg*8+4];
  }
  float cb1v[4], cw2v[4];
  #pragma unroll
  for (int nt=0;nt<4;nt++){ cb1v[nt]=sCB1p[nt*16+ln]; cw2v[nt]=sCW2[nt*16+ln]; }

  // ---- main loop: wave wv owns node i = ib*8+wv; NO barriers ----
  for (int ib=0; ib<8; ib++){
    const int i = ib*8 + wv;
    {
      float dx=sPX[i]-sPX[lane], dy=sPY[i]-sPY[lane], dz=sPZ[i]-sPZ[lane];
      sDsq[wv][lane] = dx*dx+dy*dy+dz*dz;
    }
    float ab8[2][8];
    #pragma unroll
    for (int kb=0;kb<2;kb++){
      *(float4*)&ab8[kb][0] = *(const float4*)&sAB[i*64 + kb*32+lg*8];
      *(float4*)&ab8[kb][4] = *(const float4*)&sAB[i*64 + kb*32+lg*8+4];
    }
    float trs[2][8];
    #pragma unroll
    for (int kb=0;kb<2;kb++)
      #pragma unroll
      for (int e=0;e<8;e++) trs[kb][e]=0.f;

    float sw=0.f, swx=0.f, swy=0.f, swz=0.f;

    #pragma unroll
    for (int jt=0;jt<4;jt++){
      const int j = jt*16 + ln;
      const float dq = sDsq[wv][j];
      f32x4 a4[4];
      #pragma unroll
      for (int nt=0;nt<4;nt++) a4[nt] = f32x4{0.f,0.f,0.f,0.f};

      #pragma unroll
      for (int kb=0;kb<2;kb++){
        bf16x8 c8 = *(const bf16x8*)&sC[j*72 + kb*32 + lg*8];
        bf16x8 t8;
        #pragma unroll
        for (int e=0;e<8;e++){
          float v = ab8[kb][e] + (float)c8[e] + dq*w18[kb][e];
          v = fmaxf(v, 0.f);
          trs[kb][e] += v;
          t8[e] = (__bf16)v;
        }
        #pragma unroll
        for (int nt=0;nt<4;nt++)
          a4[nt] = mfma16(t8, bW3[nt][kb], a4[nt]);
      }

      // epilogue slice for this jt: w_j = relu(U+cb1')·cw2, 16-lane butterfly
      float wr[4];
      #pragma unroll
      for (int r=0;r<4;r++){
        float p = 0.f;
        #pragma unroll
        for (int nt=0;nt<4;nt++){
          float u = a4[nt][r] + cb1v[nt];
          p += fmaxf(u, 0.f)*cw2v[nt];
        }
        p += __shfl_xor(p,1); p += __shfl_xor(p,2);
        p += __shfl_xor(p,4); p += __shfl_xor(p,8);
        wr[r] = p;
      }
      #pragma unroll
      for (int r=0;r<4;r++){
        int jj = jt*16 + lg*4 + r;
        sw  += wr[r];
        swx += wr[r]*sPX[jj];
        swy += wr[r]*sPY[jj];
        swz += wr[r]*sPZ[jj];
      }
    }

    // Trow: butterfly over 16 j-lanes, 4 lanes store bf16x8
    #pragma unroll
    for (int kb=0;kb<2;kb++)
      #pragma unroll
      for (int e=0;e<8;e++){
        float s = trs[kb][e];
        s += __shfl_xor(s,1); s += __shfl_xor(s,2);
        s += __shfl_xor(s,4); s += __shfl_xor(s,8);
        trs[kb][e] = s;
      }
    if (ln == 0){
      #pragma unroll
      for (int kb=0;kb<2;kb++){
        bf16x8 t8;
        #pragma unroll
        for (int e=0;e<8;e++) t8[e] = (__bf16)trs[kb][e];
        *(bf16x8*)&sTr[i*72 + kb*32 + lg*8] = t8;
      }
    }

    sw  += __shfl_xor(sw,16);  sw  += __shfl_xor(sw,32);
    swx += __shfl_xor(swx,16); swx += __shfl_xor(swx,32);
    swy += __shfl_xor(swy,16); swy += __shfl_xor(swy,32);
    swz += __shfl_xor(swz,16); swz += __shfl_xor(swz,32);
    if (lane == 0){
      float* o = out + (bs*64 + i)*6;
      o[0] = sPX[i] + (sPX[i]*sw - swx)*(1.f/64.f);
      o[1] = sPY[i] + (sPY[i]*sw - swy)*(1.f/64.f);
      o[2] = sPZ[i] + (sPZ[i]*sw - swz)*(1.f/64.f);
    }
  }

  // ---- batched m_i = Trow@W2 + 64*b2 ----
  __syncthreads();
  #pragma unroll
  for (int t2=0;t2<2;t2++){
    int t  = wv*2 + t2;
    int it = t>>2, nt = t&3;
    f32x4 a2 = f32x4{0.f,0.f,0.f,0.f};
    #pragma unroll
    for (int kb=0;kb<2;kb++){
      bf16x8 a8 = *(const bf16x8*)&sTr [(it*16+ln)*72 + kb*32 + lg*8];
      bf16x8 b8 = *(const bf16x8*)&sW2t[(nt*16+ln)*72 + kb*32 + lg*8];
      a2 = mfma16(a8, b8, a2);
    }
    int n = nt*16 + ln;
    float b2n = 64.f*sB2[n];
    #pragma unroll
    for (int r=0;r<4;r++){
      int i = it*16 + lg*4 + r;
      ws_mi[(bs*64 + i)*64 + n] = a2[r] + b2n;
    }
  }
}

__global__ __launch_bounds__(256)
void egnn_node_kernel(const float* __restrict__ x,
    const float* __restrict__ emb_w,  const float* __restrict__ emb_b,
    const float* __restrict__ node_w1,const float* __restrict__ node_b1,
    const float* __restrict__ node_w2,const float* __restrict__ node_b2,
    const float* __restrict__ final_w,const float* __restrict__ final_b,
    float* __restrict__ out, const float* __restrict__ ws_mi)
{
  __shared__ __align__(16) float sHt [64*64];
  __shared__ __align__(16) float sMIt[64*68];
  __shared__ __align__(16) float sNW1[128*64];
  __shared__ __align__(16) float sNW2[64*64];
  __shared__ __align__(16) float sZt [64*68];
  __shared__ float sXL[384], sEW[384], sEB[64], sNB1[64], sNB2[64];
  __shared__ float sFW[64*3], sFB[3];

  const int bs = blockIdx.x, tid = threadIdx.x;
  const float* xg = x + bs*64*6;

  for (int q=tid; q<384; q+=256){ sXL[q]=xg[q]; sEW[q]=emb_w[q]; }
  if (tid < 64){ sEB[tid]=emb_b[tid]; sNB1[tid]=node_b1[tid]; sNB2[tid]=node_b2[tid]; }
  if (tid < 192) sFW[tid] = final_w[(tid/3)*6 + 3 + (tid%3)];
  if (tid < 3)   sFB[tid] = final_b[3+tid];
  {
    const float4* g1 = (const float4*)node_w1; float4* d1 = (float4*)sNW1;
    #pragma unroll
    for (int e=0;e<8;e++) d1[tid + e*256] = g1[tid + e*256];
    const float4* g2 = (const float4*)node_w2; float4* d2 = (float4*)sNW2;
    #pragma unroll
    for (int e=0;e<4;e++) d2[tid + e*256] = g2[tid + e*256];
  }
  const float* mig = ws_mi + bs*4096;
  #pragma unroll
  for (int e=0;e<16;e++){
    int idx = tid + e*256; int iN = idx>>6, n = idx&63;
    sMIt[n*68 + iN] = mig[idx];
  }
  __syncthreads();
  #pragma unroll
  for (int e=0;e<16;e++){
    int idx = tid + e*256; int m = idx>>6, j = idx&63;
    float v = sEB[m];
    #pragma unroll
    for (int d=0;d<6;d++) v += sXL[j*6+d]*sEW[d*64+m];
    sHt[idx] = v;
  }
  __syncthreads();

  const int tj = tid>>4, tn = tid&15;
  {
    float acc[16] = {};
    #pragma unroll 8
    for (int k=0;k<64;k++){
      float4 av = *(const float4*)&sHt [k*64 + 4*tj];
      float4 bv = *(const float4*)&sNW1[k*64 + 4*tn];
      fma4x4(acc, av, bv);
    }
    #pragma unroll 8
    for (int k=0;k<64;k++){
      float4 av = *(const float4*)&sMIt[k*68 + 4*tj];
      float4 bv = *(const float4*)&sNW1[(64+k)*64 + 4*tn];
      fma4x4(acc, av, bv);
    }
    #pragma unroll
    for (int c=0;c<4;c++){
      float nb = sNB1[4*tn+c];
      float4 v = make_float4(fmaxf(acc[0+c]+nb,0.f), fmaxf(acc[4+c]+nb,0.f),
                             fmaxf(acc[8+c]+nb,0.f), fmaxf(acc[12+c]+nb,0.f));
      *(float4*)&sZt[(4*tn+c)*68 + 4*tj] = v;
    }
  }
  __syncthreads();
  {
    float acc[16] = {};
    #pragma unroll 8
    for (int k=0;k<64;k++){
      float4 av = *(const float4*)&sZt [k*68 + 4*tj];
      float4 bv = *(const float4*)&sNW2[k*64 + 4*tn];
      fma4x4(acc, av, bv);
    }
    float fv[4][3] = {};
    #pragma unroll
    for (int r=0;r<4;r++){
      #pragma unroll
      for (int c=0;c<4;c++){
        int n = 4*tn+c, j = 4*tj+r;
        float hn = acc[r*4+c] + sHt[n*64 + j] + sNB2[n];
        fv[r][0] += hn*sFW[n*3+0];
        fv[r][1] += hn*sFW[n*3+1];
        fv[r][2] += hn*sFW[n*3+2];
      }
    }
    #pragma unroll
    for (int off=1; off<16; off<<=1){
      #pragma unroll
      for (int r=0;r<4;r++){
        fv[r][0] += __shfl_xor(fv[r][0], off);
        fv[r][1] += __shfl_xor(fv[r][1], off);
        fv[r][2] += __shfl_xor(fv[r][2], off);
      }
    }
    if (tn == 0){
      #pragma unroll
      for (int r=0;r<4;r++){
        int j = 4*tj+r; int base = (bs*64+j)*6;
        #pragma unroll
        for (int d=0;d<3;d++)
          out[base+3+d] = xg[j*6+3+d] + sFB[d] + fv[r][d];
      }
    }
  }
}

extern "C" void kernel_launch(void* const* d_in, const int* in_sizes, int n_in,
                              void* d_out, int out_size, void* d_ws, size_t ws_size,
                              hipStream_t stream)
{
  const float* x        = (const float*)d_in[0];
  const float* emb_w    = (const float*)d_in[1];
  const float* emb_b    = (const float*)d_in[2];
  const float* edge_w1  = (const float*)d_in[3];
  const float* edge_b1  = (const float*)d_in[4];
  const float* edge_w2  = (const float*)d_in[5];
  const float* edge_b2  = (const float*)d_in[6];
  const float* node_w1  = (const float*)d_in[7];
  const float* node_b1  = (const float*)d_in[8];
  const float* node_w2  = (const float*)d_in[9];
  const float* node_b2  = (const float*)d_in[10];
  const float* coord_w1 = (const float*)d_in[11];
  const float* coord_b1 = (const float*)d_in[12];
  const float* coord_w2 = (const float*)d_in[13];
  const float* final_w  = (const float*)d_in[14];
  const float* final_b  = (const float*)d_in[15];
  float* out   = (float*)d_out;
  float* ws_mi = (float*)d_ws;   // 256*64*64 f32 = 4 MB

  egnn_edge_mfma<<<NG, 512, 0, stream>>>(x, emb_w, emb_b,
      edge_w1, edge_b1, edge_w2, edge_b2, coord_w1, coord_b1, coord_w2,
      out, ws_mi);
  egnn_node_kernel<<<NG, 256, 0, stream>>>(x, emb_w, emb_b,
      node_w1, node_b1, node_w2, node_b2, final_w, final_b,
      out, ws_mi);
}

// Round 5
// 82.662 us; speedup vs baseline: 4.8343x; 1.0518x over previous
//
#include <hip/hip_runtime.h>

// EquivariantGNN: 256 graphs, N=64 nodes, HID=64, fp32 in/out.
// R5: (1) edge: amdgpu_waves_per_eu(1) -> VGPR budget 256 (LDS already caps
//     occupancy at 2 waves/SIMD, so regs are free) to kill residual spill.
//     (2) node: bf16 MFMA for z=relu([h|mi]@nw1+nb1); vel folded as
//     vel + h@fw3 + z@(nw2@fw3) + (nb2@fw3+fb3) -- z@nw2 GEMM eliminated.

#define NG 256

typedef __attribute__((ext_vector_type(4))) float f32x4;
typedef __attribute__((ext_vector_type(8))) __bf16 bf16x8;

__device__ __forceinline__ f32x4 mfma16(bf16x8 a, bf16x8 b, f32x4 c){
  return __builtin_amdgcn_mfma_f32_16x16x32_bf16(a, b, c, 0, 0, 0);
}

__device__ __forceinline__ void fma4x4(float* acc, float4 a, float4 b){
  acc[0]  += a.x*b.x; acc[1]  += a.x*b.y; acc[2]  += a.x*b.z; acc[3]  += a.x*b.w;
  acc[4]  += a.y*b.x; acc[5]  += a.y*b.y; acc[6]  += a.y*b.z; acc[7]  += a.y*b.w;
  acc[8]  += a.z*b.x; acc[9]  += a.z*b.y; acc[10] += a.z*b.z; acc[11] += a.z*b.w;
  acc[12] += a.w*b.x; acc[13] += a.w*b.y; acc[14] += a.w*b.z; acc[15] += a.w*b.w;
}

__global__ __launch_bounds__(512) __attribute__((amdgpu_waves_per_eu(1)))
void egnn_edge_mfma(const float* __restrict__ x,
    const float* __restrict__ emb_w,  const float* __restrict__ emb_b,
    const float* __restrict__ edge_w1,const float* __restrict__ edge_b1,
    const float* __restrict__ edge_w2,const float* __restrict__ edge_b2,
    const float* __restrict__ coord_w1,const float* __restrict__ coord_b1,
    const float* __restrict__ coord_w2,
    float* __restrict__ out, float* __restrict__ ws_mi)
{
  // persistent (main loop)
  __shared__ __align__(16) float  sAB [64*64];   // a_i[k]+b1[k], f32 [i][k]
  __shared__ __align__(16) __bf16 sC  [64*72];   // c_j[k] bf16 [j][72]
  __shared__ __align__(16) __bf16 sW3t[64*72];   // (W2@cw1)^T [n'][k]
  __shared__ __align__(16) __bf16 sW2t[64*72];   // W2^T [n][k]
  __shared__ __align__(16) __bf16 sTr [64*72];   // Trow [i][k]
  __shared__ float sDsq[8][64];
  __shared__ float sPX[64], sPY[64], sPZ[64];
  __shared__ __align__(16) float sW1L[64];
  __shared__ float sCB1p[64], sCW2[64], sB2[64], sB1[64];
  // precompute scratch
  __shared__ __align__(16) float sW1a[64*64], sW1b[64*64], sW2T[64*64], sCW1[64*64];
  __shared__ __align__(16) float sHt[64*64];
  __shared__ float sXL[384], sEW[384], sEB[64];

  const int bs  = blockIdx.x, tid = threadIdx.x;
  const int lane = tid & 63, wv = tid >> 6;
  const float* xg = x + bs*384;

  // ---- stage ----
  if (tid < 384){ sXL[tid] = xg[tid]; sEW[tid] = emb_w[tid]; }
  if (tid < 64){
    sEB[tid] = emb_b[tid];  sB1[tid] = edge_b1[tid]; sB2[tid] = edge_b2[tid];
    sCW2[tid] = coord_w2[tid]; sW1L[tid] = edge_w1[128*64 + tid];
  } else if (tid < 128){
    int j = tid-64; sPX[j]=xg[j*6]; sPY[j]=xg[j*6+1]; sPZ[j]=xg[j*6+2];
  }
  {
    const float4* w1 = (const float4*)edge_w1;
    const float4* cw = (const float4*)coord_w1;
    float4* da=(float4*)sW1a; float4* db=(float4*)sW1b; float4* dc=(float4*)sCW1;
    #pragma unroll
    for (int e=0;e<2;e++){ int q=tid+e*512; da[q]=w1[q]; db[q]=w1[1024+q]; dc[q]=cw[q]; }
  }
  // W2 transposed into LDS
  #pragma unroll
  for (int e=0;e<8;e++){ int idx=tid+e*512; int n=idx>>6, k=idx&63;
    sW2T[idx] = edge_w2[k*64+n]; }   // sW2T[n*64+k] = W2[k][n]
  __syncthreads();

  // ---- h^T[m][j] (fp32) ----
  #pragma unroll
  for (int e=0;e<8;e++){
    int idx=tid+e*512; int m=idx>>6, j=idx&63;
    float v = sEB[m];
    #pragma unroll
    for (int d=0;d<6;d++) v += sXL[j*6+d]*sEW[d*64+m];
    sHt[idx] = v;
  }
  __syncthreads();

  const int g = tid>>8, tl = tid&255, tjx = tl>>4, tnx = tl&15;
  // group0: ab = h@W1a + b1 (fp32) ; group1: c = h@W1b (bf16)
  {
    float acc[16] = {};
    const float* Bm = g ? sW1b : sW1a;
    #pragma unroll 8
    for (int k=0;k<64;k++){
      float4 av = *(const float4*)&sHt[k*64 + 4*tjx];
      float4 bv = *(const float4*)&Bm [k*64 + 4*tnx];
      fma4x4(acc, av, bv);
    }
    if (g==0){
      #pragma unroll
      for (int r=0;r<4;r++)
        #pragma unroll
        for (int c=0;c<4;c++)
          sAB[(4*tjx+r)*64 + 4*tnx+c] = acc[r*4+c] + sB1[4*tnx+c];
    } else {
      #pragma unroll
      for (int r=0;r<4;r++)
        #pragma unroll
        for (int c=0;c<4;c++)
          sC[(4*tjx+r)*72 + 4*tnx+c] = (__bf16)acc[r*4+c];
    }
  }
  // group0: W3 = W2@cw1 -> sW3t bf16 ; group1: W2t bf16 + cb1' = cb1 + b2@cw1
  if (g==0){
    float acc[16] = {};
    #pragma unroll 8
    for (int k=0;k<64;k++){
      float4 av = *(const float4*)&sW2T[k*64 + 4*tjx];
      float4 bv = *(const float4*)&sCW1[k*64 + 4*tnx];
      fma4x4(acc, av, bv);
    }
    #pragma unroll
    for (int r=0;r<4;r++)
      #pragma unroll
      for (int c=0;c<4;c++)
        sW3t[(4*tnx+c)*72 + 4*tjx+r] = (__bf16)acc[r*4+c];
  } else {
    #pragma unroll
    for (int e=0;e<16;e++){ int idx=tl+e*256; sW2t[(idx>>6)*72 + (idx&63)] = (__bf16)sW2T[idx]; }
    if (tl < 64){
      float s = coord_b1[tl];
      for (int n=0;n<64;n++) s += sB2[n]*sCW1[n*64+tl];
      sCB1p[tl] = s;
    }
  }
  __syncthreads();

  const int lg = lane>>4, ln = lane&15;

  // invariants hoisted into registers
  bf16x8 bW3[4][2];
  #pragma unroll
  for (int nt=0;nt<4;nt++)
    #pragma unroll
    for (int kb=0;kb<2;kb++)
      bW3[nt][kb] = *(const bf16x8*)&sW3t[(nt*16+ln)*72 + kb*32 + lg*8];
  float w18[2][8];
  #pragma unroll
  for (int kb=0;kb<2;kb++){
    *(float4*)&w18[kb][0] = *(const float4*)&sW1L[kb*32+lg*8];
    *(float4*)&w18[kb][4] = *(const float4*)&sW1L[kb*32+lg*8+4];
  }
  float cb1v[4], cw2v[4];
  #pragma unroll
  for (int nt=0;nt<4;nt++){ cb1v[nt]=sCB1p[nt*16+ln]; cw2v[nt]=sCW2[nt*16+ln]; }

  // ---- main loop: wave wv owns node i = ib*8+wv; NO barriers ----
  for (int ib=0; ib<8; ib++){
    const int i = ib*8 + wv;
    {
      float dx=sPX[i]-sPX[lane], dy=sPY[i]-sPY[lane], dz=sPZ[i]-sPZ[lane];
      sDsq[wv][lane] = dx*dx+dy*dy+dz*dz;
    }
    float ab8[2][8];
    #pragma unroll
    for (int kb=0;kb<2;kb++){
      *(float4*)&ab8[kb][0] = *(const float4*)&sAB[i*64 + kb*32+lg*8];
      *(float4*)&ab8[kb][4] = *(const float4*)&sAB[i*64 + kb*32+lg*8+4];
    }
    float trs[2][8];
    #pragma unroll
    for (int kb=0;kb<2;kb++)
      #pragma unroll
      for (int e=0;e<8;e++) trs[kb][e]=0.f;

    float sw=0.f, swx=0.f, swy=0.f, swz=0.f;

    #pragma unroll
    for (int jt=0;jt<4;jt++){
      const int j = jt*16 + ln;
      const float dq = sDsq[wv][j];
      f32x4 a4[4];
      #pragma unroll
      for (int nt=0;nt<4;nt++) a4[nt] = f32x4{0.f,0.f,0.f,0.f};

      #pragma unroll
      for (int kb=0;kb<2;kb++){
        bf16x8 c8 = *(const bf16x8*)&sC[j*72 + kb*32 + lg*8];
        bf16x8 t8;
        #pragma unroll
        for (int e=0;e<8;e++){
          float v = ab8[kb][e] + (float)c8[e] + dq*w18[kb][e];
          v = fmaxf(v, 0.f);
          trs[kb][e] += v;
          t8[e] = (__bf16)v;
        }
        #pragma unroll
        for (int nt=0;nt<4;nt++)
          a4[nt] = mfma16(t8, bW3[nt][kb], a4[nt]);
      }

      // epilogue slice for this jt: w_j = relu(U+cb1')·cw2, 16-lane butterfly
      float wr[4];
      #pragma unroll
      for (int r=0;r<4;r++){
        float p = 0.f;
        #pragma unroll
        for (int nt=0;nt<4;nt++){
          float u = a4[nt][r] + cb1v[nt];
          p += fmaxf(u, 0.f)*cw2v[nt];
        }
        p += __shfl_xor(p,1); p += __shfl_xor(p,2);
        p += __shfl_xor(p,4); p += __shfl_xor(p,8);
        wr[r] = p;
      }
      #pragma unroll
      for (int r=0;r<4;r++){
        int jj = jt*16 + lg*4 + r;
        sw  += wr[r];
        swx += wr[r]*sPX[jj];
        swy += wr[r]*sPY[jj];
        swz += wr[r]*sPZ[jj];
      }
    }

    // Trow: butterfly over 16 j-lanes, 4 lanes store bf16x8
    #pragma unroll
    for (int kb=0;kb<2;kb++)
      #pragma unroll
      for (int e=0;e<8;e++){
        float s = trs[kb][e];
        s += __shfl_xor(s,1); s += __shfl_xor(s,2);
        s += __shfl_xor(s,4); s += __shfl_xor(s,8);
        trs[kb][e] = s;
      }
    if (ln == 0){
      #pragma unroll
      for (int kb=0;kb<2;kb++){
        bf16x8 t8;
        #pragma unroll
        for (int e=0;e<8;e++) t8[e] = (__bf16)trs[kb][e];
        *(bf16x8*)&sTr[i*72 + kb*32 + lg*8] = t8;
      }
    }

    sw  += __shfl_xor(sw,16);  sw  += __shfl_xor(sw,32);
    swx += __shfl_xor(swx,16); swx += __shfl_xor(swx,32);
    swy += __shfl_xor(swy,16); swy += __shfl_xor(swy,32);
    swz += __shfl_xor(swz,16); swz += __shfl_xor(swz,32);
    if (lane == 0){
      float* o = out + (bs*64 + i)*6;
      o[0] = sPX[i] + (sPX[i]*sw - swx)*(1.f/64.f);
      o[1] = sPY[i] + (sPY[i]*sw - swy)*(1.f/64.f);
      o[2] = sPZ[i] + (sPZ[i]*sw - swz)*(1.f/64.f);
    }
  }

  // ---- batched m_i = Trow@W2 + 64*b2 ----
  __syncthreads();
  #pragma unroll
  for (int t2=0;t2<2;t2++){
    int t  = wv*2 + t2;
    int it = t>>2, nt = t&3;
    f32x4 a2 = f32x4{0.f,0.f,0.f,0.f};
    #pragma unroll
    for (int kb=0;kb<2;kb++){
      bf16x8 a8 = *(const bf16x8*)&sTr [(it*16+ln)*72 + kb*32 + lg*8];
      bf16x8 b8 = *(const bf16x8*)&sW2t[(nt*16+ln)*72 + kb*32 + lg*8];
      a2 = mfma16(a8, b8, a2);
    }
    int n = nt*16 + ln;
    float b2n = 64.f*sB2[n];
    #pragma unroll
    for (int r=0;r<4;r++){
      int i = it*16 + lg*4 + r;
      ws_mi[(bs*64 + i)*64 + n] = a2[r] + b2n;
    }
  }
}

// Node kernel: z = relu([h|mi]@nw1+nb1) via MFMA (K=128);
// vel_out = vel + h@fw3 + z@(nw2@fw3) + (nb2@fw3 + fb3).
__global__ __launch_bounds__(256)
void egnn_node_mfma(const float* __restrict__ x,
    const float* __restrict__ emb_w,  const float* __restrict__ emb_b,
    const float* __restrict__ node_w1,const float* __restrict__ node_b1,
    const float* __restrict__ node_w2,const float* __restrict__ node_b2,
    const float* __restrict__ final_w,const float* __restrict__ final_b,
    float* __restrict__ out, const float* __restrict__ ws_mi)
{
  __shared__ __align__(16) float  sHt [64*64];    // h^T [m][j] f32
  __shared__ __align__(16) __bf16 sAb [64*136];   // A rows: [j][ h(0:64) | mi(64:128) ]
  __shared__ __align__(16) __bf16 sNW1t[64*136];  // nw1^T [n][kk]
  __shared__ __align__(16) float sNW2[64*64];
  __shared__ float sG  [64*4];   // (nw2@fw3)[k][d]
  __shared__ float sHf3[64*4];   // (h@fw3)[j][d]
  __shared__ float sFW3[64*4];   // fw[:,3:6]
  __shared__ float sCvec[4];
  __shared__ float sXL[384], sEW[384], sEB[64], sNB1[64], sNB2[64];

  const int bs=blockIdx.x, tid=threadIdx.x;
  const int lane=tid&63, wv=tid>>6, ln=lane&15, lg=lane>>4;
  const float* xg = x + bs*384;

  for (int q=tid;q<384;q+=256){ sXL[q]=xg[q]; sEW[q]=emb_w[q]; }
  if (tid<64){ sEB[tid]=emb_b[tid]; sNB1[tid]=node_b1[tid]; sNB2[tid]=node_b2[tid]; }
  if (tid<192){ int n=tid&63, d=tid>>6; sFW3[n*4+d]=final_w[n*6+3+d]; }
  { const float4* g2=(const float4*)node_w2; float4* d2=(float4*)sNW2;
    #pragma unroll
    for (int e=0;e<4;e++) d2[tid+e*256]=g2[tid+e*256]; }
  #pragma unroll
  for (int e=0;e<32;e++){ int idx=tid+e*256; int kk=idx>>6, n=idx&63;
    sNW1t[n*136+kk]=(__bf16)node_w1[idx]; }
  { const float* mig = ws_mi + bs*4096;
    #pragma unroll
    for (int e=0;e<16;e++){ int idx=tid+e*256; int i=idx>>6, n=idx&63;
      sAb[i*136+64+n]=(__bf16)mig[idx]; } }
  __syncthreads();

  // h: thread (j, 16 m's) -> sHt f32 + sAb bf16
  { int j=tid&63, mb=tid>>6;
    #pragma unroll
    for (int mm=0;mm<16;mm++){ int m=mb*16+mm;
      float v=sEB[m];
      #pragma unroll
      for (int d=0;d<6;d++) v+=sXL[j*6+d]*sEW[d*64+m];
      sHt[m*64+j]=v; sAb[j*136+m]=(__bf16)v; } }
  __syncthreads();

  // G = nw2@fw3 (skewed n to dodge bank conflicts), hf3 = h@fw3, cvec
  if (tid<192){
    int k=tid&63, d=tid>>6;
    float gacc=0.f, s=0.f;
    for (int nn=0;nn<64;nn++){
      int n=(nn+k)&63;
      gacc += sNW2[k*64+n]*sFW3[n*4+d];
      s    += sHt[nn*64+k]*sFW3[nn*4+d];
    }
    sG[k*4+d]=gacc; sHf3[k*4+d]=s;
  } else if (tid<195){
    int d=tid-192; float c=final_b[3+d];
    for (int n=0;n<64;n++) c+=sNB2[n]*sFW3[n*4+d];
    sCvec[d]=c;
  }
  __syncthreads();

  // z GEMM: wave wv owns 16-row j-tile, K=128, N=64
  f32x4 acc[4];
  #pragma unroll
  for (int nt=0;nt<4;nt++) acc[nt]=f32x4{0.f,0.f,0.f,0.f};
  #pragma unroll
  for (int kb=0;kb<4;kb++){
    bf16x8 a8 = *(const bf16x8*)&sAb[(wv*16+ln)*136 + kb*32 + lg*8];
    #pragma unroll
    for (int nt=0;nt<4;nt++){
      bf16x8 b8 = *(const bf16x8*)&sNW1t[(nt*16+ln)*136 + kb*32 + lg*8];
      acc[nt]=mfma16(a8,b8,acc[nt]);
    }
  }
  // vel epilogue: p[r][d] = sum_n relu(z)*G[n][d], butterfly over 16 n-lanes
  float p[4][3];
  #pragma unroll
  for(int r=0;r<4;r++){ p[r][0]=0.f; p[r][1]=0.f; p[r][2]=0.f; }
  #pragma unroll
  for (int nt=0;nt<4;nt++){
    int n=nt*16+ln;
    float zb=sNB1[n];
    float g0=sG[n*4], g1=sG[n*4+1], g2=sG[n*4+2];
    #pragma unroll
    for (int r=0;r<4;r++){
      float u=fmaxf(acc[nt][r]+zb,0.f);
      p[r][0]+=u*g0; p[r][1]+=u*g1; p[r][2]+=u*g2;
    }
  }
  #pragma unroll
  for (int off=1;off<16;off<<=1)
    #pragma unroll
    for (int r=0;r<4;r++){
      p[r][0]+=__shfl_xor(p[r][0],off);
      p[r][1]+=__shfl_xor(p[r][1],off);
      p[r][2]+=__shfl_xor(p[r][2],off);
    }
  if (ln==0){
    #pragma unroll
    for (int r=0;r<4;r++){
      int j=wv*16+lg*4+r; int base=(bs*64+j)*6;
      #pragma unroll
      for (int d=0;d<3;d++)
        out[base+3+d]=xg[j*6+3+d]+sHf3[j*4+d]+sCvec[d]+p[r][d];
    }
  }
}

extern "C" void kernel_launch(void* const* d_in, const int* in_sizes, int n_in,
                              void* d_out, int out_size, void* d_ws, size_t ws_size,
                              hipStream_t stream)
{
  const float* x        = (const float*)d_in[0];
  const float* emb_w    = (const float*)d_in[1];
  const float* emb_b    = (const float*)d_in[2];
  const float* edge_w1  = (const float*)d_in[3];
  const float* edge_b1  = (const float*)d_in[4];
  const float* edge_w2  = (const float*)d_in[5];
  const float* edge_b2  = (const float*)d_in[6];
  const float* node_w1  = (const float*)d_in[7];
  const float* node_b1  = (const float*)d_in[8];
  const float* node_w2  = (const float*)d_in[9];
  const float* node_b2  = (const float*)d_in[10];
  const float* coord_w1 = (const float*)d_in[11];
  const float* coord_b1 = (const float*)d_in[12];
  const float* coord_w2 = (const float*)d_in[13];
  const float* final_w  = (const float*)d_in[14];
  const float* final_b  = (const float*)d_in[15];
  float* out   = (float*)d_out;
  float* ws_mi = (float*)d_ws;   // 256*64*64 f32 = 4 MB

  egnn_edge_mfma<<<NG, 512, 0, stream>>>(x, emb_w, emb_b,
      edge_w1, edge_b1, edge_w2, edge_b2, coord_w1, coord_b1, coord_w2,
      out, ws_mi);
  egnn_node_mfma<<<NG, 256, 0, stream>>>(x, emb_w, emb_b,
      node_w1, node_b1, node_w2, node_b2, final_w, final_b,
      out, ws_mi);
}

// Round 6
// 70.599 us; speedup vs baseline: 5.6603x; 1.1709x over previous
//
#include <hip/hip_runtime.h>

// EquivariantGNN: 256 graphs, N=64 nodes, HID=64, fp32 in/out.
// R6: kill spill STRUCTURALLY. R4/R5 attributes didn't lift the 128-VGPR cap;
// census says long-lived hoists (bW3 32r, w18 16r, cb1/cw2 8r) push live set
// to ~135. De-hoist them to in-loop LDS reads (broadcast / 2-way aliased ->
// free); live set ~80 regs -> no spill. Node kernel unchanged (R5 MFMA).

#define NG 256

typedef __attribute__((ext_vector_type(4))) float f32x4;
typedef __attribute__((ext_vector_type(8))) __bf16 bf16x8;

__device__ __forceinline__ f32x4 mfma16(bf16x8 a, bf16x8 b, f32x4 c){
  return __builtin_amdgcn_mfma_f32_16x16x32_bf16(a, b, c, 0, 0, 0);
}

__device__ __forceinline__ void fma4x4(float* acc, float4 a, float4 b){
  acc[0]  += a.x*b.x; acc[1]  += a.x*b.y; acc[2]  += a.x*b.z; acc[3]  += a.x*b.w;
  acc[4]  += a.y*b.x; acc[5]  += a.y*b.y; acc[6]  += a.y*b.z; acc[7]  += a.y*b.w;
  acc[8]  += a.z*b.x; acc[9]  += a.z*b.y; acc[10] += a.z*b.z; acc[11] += a.z*b.w;
  acc[12] += a.w*b.x; acc[13] += a.w*b.y; acc[14] += a.w*b.z; acc[15] += a.w*b.w;
}

__global__ __launch_bounds__(512)
void egnn_edge_mfma(const float* __restrict__ x,
    const float* __restrict__ emb_w,  const float* __restrict__ emb_b,
    const float* __restrict__ edge_w1,const float* __restrict__ edge_b1,
    const float* __restrict__ edge_w2,const float* __restrict__ edge_b2,
    const float* __restrict__ coord_w1,const float* __restrict__ coord_b1,
    const float* __restrict__ coord_w2,
    float* __restrict__ out, float* __restrict__ ws_mi)
{
  // persistent (main loop)
  __shared__ __align__(16) float  sAB [64*64];   // a_i[k]+b1[k], f32 [i][k]
  __shared__ __align__(16) __bf16 sC  [64*72];   // c_j[k] bf16 [j][72]
  __shared__ __align__(16) __bf16 sW3t[64*72];   // (W2@cw1)^T [n'][k]
  __shared__ __align__(16) __bf16 sW2t[64*72];   // W2^T [n][k]
  __shared__ __align__(16) __bf16 sTr [64*72];   // Trow [i][k]
  __shared__ float sDsq[8][64];
  __shared__ float sPX[64], sPY[64], sPZ[64];
  __shared__ __align__(16) float sW1L[64];
  __shared__ float sCB1p[64], sCW2[64], sB2[64], sB1[64];
  // precompute scratch
  __shared__ __align__(16) float sW1a[64*64], sW1b[64*64], sW2T[64*64], sCW1[64*64];
  __shared__ __align__(16) float sHt[64*64];
  __shared__ float sXL[384], sEW[384], sEB[64];

  const int bs  = blockIdx.x, tid = threadIdx.x;
  const int lane = tid & 63, wv = tid >> 6;
  const float* xg = x + bs*384;

  // ---- stage ----
  if (tid < 384){ sXL[tid] = xg[tid]; sEW[tid] = emb_w[tid]; }
  if (tid < 64){
    sEB[tid] = emb_b[tid];  sB1[tid] = edge_b1[tid]; sB2[tid] = edge_b2[tid];
    sCW2[tid] = coord_w2[tid]; sW1L[tid] = edge_w1[128*64 + tid];
  } else if (tid < 128){
    int j = tid-64; sPX[j]=xg[j*6]; sPY[j]=xg[j*6+1]; sPZ[j]=xg[j*6+2];
  }
  {
    const float4* w1 = (const float4*)edge_w1;
    const float4* cw = (const float4*)coord_w1;
    float4* da=(float4*)sW1a; float4* db=(float4*)sW1b; float4* dc=(float4*)sCW1;
    #pragma unroll
    for (int e=0;e<2;e++){ int q=tid+e*512; da[q]=w1[q]; db[q]=w1[1024+q]; dc[q]=cw[q]; }
  }
  // W2 transposed into LDS
  #pragma unroll
  for (int e=0;e<8;e++){ int idx=tid+e*512; int n=idx>>6, k=idx&63;
    sW2T[idx] = edge_w2[k*64+n]; }   // sW2T[n*64+k] = W2[k][n]
  __syncthreads();

  // ---- h^T[m][j] (fp32) ----
  #pragma unroll
  for (int e=0;e<8;e++){
    int idx=tid+e*512; int m=idx>>6, j=idx&63;
    float v = sEB[m];
    #pragma unroll
    for (int d=0; d<6; d++) v += sXL[j*6+d]*sEW[d*64+m];
    sHt[idx] = v;
  }
  __syncthreads();

  const int g = tid>>8, tl = tid&255, tjx = tl>>4, tnx = tl&15;
  // group0: ab = h@W1a + b1 (fp32) ; group1: c = h@W1b (bf16)
  {
    float acc[16] = {};
    const float* Bm = g ? sW1b : sW1a;
    #pragma unroll 8
    for (int k=0;k<64;k++){
      float4 av = *(const float4*)&sHt[k*64 + 4*tjx];
      float4 bv = *(const float4*)&Bm [k*64 + 4*tnx];
      fma4x4(acc, av, bv);
    }
    if (g==0){
      #pragma unroll
      for (int r=0;r<4;r++)
        #pragma unroll
        for (int c=0;c<4;c++)
          sAB[(4*tjx+r)*64 + 4*tnx+c] = acc[r*4+c] + sB1[4*tnx+c];
    } else {
      #pragma unroll
      for (int r=0;r<4;r++)
        #pragma unroll
        for (int c=0;c<4;c++)
          sC[(4*tjx+r)*72 + 4*tnx+c] = (__bf16)acc[r*4+c];
    }
  }
  // group0: W3 = W2@cw1 -> sW3t bf16 ; group1: W2t bf16 + cb1' = cb1 + b2@cw1
  if (g==0){
    float acc[16] = {};
    #pragma unroll 8
    for (int k=0;k<64;k++){
      float4 av = *(const float4*)&sW2T[k*64 + 4*tjx];
      float4 bv = *(const float4*)&sCW1[k*64 + 4*tnx];
      fma4x4(acc, av, bv);
    }
    #pragma unroll
    for (int r=0;r<4;r++)
      #pragma unroll
      for (int c=0;c<4;c++)
        sW3t[(4*tnx+c)*72 + 4*tjx+r] = (__bf16)acc[r*4+c];
  } else {
    #pragma unroll
    for (int e=0;e<16;e++){ int idx=tl+e*256; sW2t[(idx>>6)*72 + (idx&63)] = (__bf16)sW2T[idx]; }
    if (tl < 64){
      float s = coord_b1[tl];
      for (int n=0;n<64;n++) s += sB2[n]*sCW1[n*64+tl];
      sCB1p[tl] = s;
    }
  }
  __syncthreads();

  const int lg = lane>>4, ln = lane&15;

  // ---- main loop: wave wv owns node i = ib*8+wv; NO barriers, NO long-lived
  //      register hoists (everything re-read from LDS; broadcast or 2-way) ----
  for (int ib=0; ib<8; ib++){
    const int i = ib*8 + wv;
    {
      float dx=sPX[i]-sPX[lane], dy=sPY[i]-sPY[lane], dz=sPZ[i]-sPZ[lane];
      sDsq[wv][lane] = dx*dx+dy*dy+dz*dz;
    }
    float ab8[2][8];
    #pragma unroll
    for (int kb=0;kb<2;kb++){
      *(float4*)&ab8[kb][0] = *(const float4*)&sAB[i*64 + kb*32+lg*8];
      *(float4*)&ab8[kb][4] = *(const float4*)&sAB[i*64 + kb*32+lg*8+4];
    }
    float trs[2][8];
    #pragma unroll
    for (int kb=0;kb<2;kb++)
      #pragma unroll
      for (int e=0;e<8;e++) trs[kb][e]=0.f;

    float sw=0.f, swx=0.f, swy=0.f, swz=0.f;

    #pragma unroll
    for (int jt=0;jt<4;jt++){
      const int j = jt*16 + ln;
      const float dq = sDsq[wv][j];
      f32x4 a4[4];
      #pragma unroll
      for (int nt=0;nt<4;nt++) a4[nt] = f32x4{0.f,0.f,0.f,0.f};

      #pragma unroll
      for (int kb=0;kb<2;kb++){
        bf16x8 c8 = *(const bf16x8*)&sC[j*72 + kb*32 + lg*8];
        float w8[8];
        *(float4*)&w8[0] = *(const float4*)&sW1L[kb*32+lg*8];
        *(float4*)&w8[4] = *(const float4*)&sW1L[kb*32+lg*8+4];
        bf16x8 t8;
        #pragma unroll
        for (int e=0;e<8;e++){
          float v = ab8[kb][e] + (float)c8[e] + dq*w8[e];
          v = fmaxf(v, 0.f);
          trs[kb][e] += v;
          t8[e] = (__bf16)v;
        }
        #pragma unroll
        for (int nt=0;nt<4;nt++){
          bf16x8 b8 = *(const bf16x8*)&sW3t[(nt*16+ln)*72 + kb*32 + lg*8];
          a4[nt] = mfma16(t8, b8, a4[nt]);
        }
      }

      // epilogue slice for this jt: w_j = relu(U+cb1')·cw2, 16-lane butterfly
      float wr[4];
      #pragma unroll
      for (int r=0;r<4;r++){
        float p = 0.f;
        #pragma unroll
        for (int nt=0;nt<4;nt++){
          int n = nt*16 + ln;
          float u = a4[nt][r] + sCB1p[n];
          p += fmaxf(u, 0.f)*sCW2[n];
        }
        p += __shfl_xor(p,1); p += __shfl_xor(p,2);
        p += __shfl_xor(p,4); p += __shfl_xor(p,8);
        wr[r] = p;
      }
      #pragma unroll
      for (int r=0;r<4;r++){
        int jj = jt*16 + lg*4 + r;
        sw  += wr[r];
        swx += wr[r]*sPX[jj];
        swy += wr[r]*sPY[jj];
        swz += wr[r]*sPZ[jj];
      }
    }

    // Trow: butterfly over 16 j-lanes, 4 lanes store bf16x8
    #pragma unroll
    for (int kb=0;kb<2;kb++)
      #pragma unroll
      for (int e=0;e<8;e++){
        float s = trs[kb][e];
        s += __shfl_xor(s,1); s += __shfl_xor(s,2);
        s += __shfl_xor(s,4); s += __shfl_xor(s,8);
        trs[kb][e] = s;
      }
    if (ln == 0){
      #pragma unroll
      for (int kb=0;kb<2;kb++){
        bf16x8 t8;
        #pragma unroll
        for (int e=0;e<8;e++) t8[e] = (__bf16)trs[kb][e];
        *(bf16x8*)&sTr[i*72 + kb*32 + lg*8] = t8;
      }
    }

    sw  += __shfl_xor(sw,16);  sw  += __shfl_xor(sw,32);
    swx += __shfl_xor(swx,16); swx += __shfl_xor(swx,32);
    swy += __shfl_xor(swy,16); swy += __shfl_xor(swy,32);
    swz += __shfl_xor(swz,16); swz += __shfl_xor(swz,32);
    if (lane == 0){
      float* o = out + (bs*64 + i)*6;
      o[0] = sPX[i] + (sPX[i]*sw - swx)*(1.f/64.f);
      o[1] = sPY[i] + (sPY[i]*sw - swy)*(1.f/64.f);
      o[2] = sPZ[i] + (sPZ[i]*sw - swz)*(1.f/64.f);
    }
  }

  // ---- batched m_i = Trow@W2 + 64*b2 ----
  __syncthreads();
  #pragma unroll
  for (int t2=0;t2<2;t2++){
    int t  = wv*2 + t2;
    int it = t>>2, nt = t&3;
    f32x4 a2 = f32x4{0.f,0.f,0.f,0.f};
    #pragma unroll
    for (int kb=0;kb<2;kb++){
      bf16x8 a8 = *(const bf16x8*)&sTr [(it*16+ln)*72 + kb*32 + lg*8];
      bf16x8 b8 = *(const bf16x8*)&sW2t[(nt*16+ln)*72 + kb*32 + lg*8];
      a2 = mfma16(a8, b8, a2);
    }
    int n = nt*16 + ln;
    float b2n = 64.f*sB2[n];
    #pragma unroll
    for (int r=0;r<4;r++){
      int i = it*16 + lg*4 + r;
      ws_mi[(bs*64 + i)*64 + n] = a2[r] + b2n;
    }
  }
}

// Node kernel: z = relu([h|mi]@nw1+nb1) via MFMA (K=128);
// vel_out = vel + h@fw3 + z@(nw2@fw3) + (nb2@fw3 + fb3).
__global__ __launch_bounds__(256)
void egnn_node_mfma(const float* __restrict__ x,
    const float* __restrict__ emb_w,  const float* __restrict__ emb_b,
    const float* __restrict__ node_w1,const float* __restrict__ node_b1,
    const float* __restrict__ node_w2,const float* __restrict__ node_b2,
    const float* __restrict__ final_w,const float* __restrict__ final_b,
    float* __restrict__ out, const float* __restrict__ ws_mi)
{
  __shared__ __align__(16) float  sHt [64*64];    // h^T [m][j] f32
  __shared__ __align__(16) __bf16 sAb [64*136];   // A rows: [j][ h(0:64) | mi(64:128) ]
  __shared__ __align__(16) __bf16 sNW1t[64*136];  // nw1^T [n][kk]
  __shared__ __align__(16) float sNW2[64*64];
  __shared__ float sG  [64*4];   // (nw2@fw3)[k][d]
  __shared__ float sHf3[64*4];   // (h@fw3)[j][d]
  __shared__ float sFW3[64*4];   // fw[:,3:6]
  __shared__ float sCvec[4];
  __shared__ float sXL[384], sEW[384], sEB[64], sNB1[64], sNB2[64];

  const int bs=blockIdx.x, tid=threadIdx.x;
  const int lane=tid&63, wv=tid>>6, ln=lane&15, lg=lane>>4;
  const float* xg = x + bs*384;

  for (int q=tid;q<384;q+=256){ sXL[q]=xg[q]; sEW[q]=emb_w[q]; }
  if (tid<64){ sEB[tid]=emb_b[tid]; sNB1[tid]=node_b1[tid]; sNB2[tid]=node_b2[tid]; }
  if (tid<192){ int n=tid&63, d=tid>>6; sFW3[n*4+d]=final_w[n*6+3+d]; }
  { const float4* g2=(const float4*)node_w2; float4* d2=(float4*)sNW2;
    #pragma unroll
    for (int e=0;e<4;e++) d2[tid+e*256]=g2[tid+e*256]; }
  #pragma unroll
  for (int e=0;e<32;e++){ int idx=tid+e*256; int kk=idx>>6, n=idx&63;
    sNW1t[n*136+kk]=(__bf16)node_w1[idx]; }
  { const float* mig = ws_mi + bs*4096;
    #pragma unroll
    for (int e=0;e<16;e++){ int idx=tid+e*256; int i=idx>>6, n=idx&63;
      sAb[i*136+64+n]=(__bf16)mig[idx]; } }
  __syncthreads();

  // h: thread (j, 16 m's) -> sHt f32 + sAb bf16
  { int j=tid&63, mb=tid>>6;
    #pragma unroll
    for (int mm=0;mm<16;mm++){ int m=mb*16+mm;
      float v=sEB[m];
      #pragma unroll
      for (int d=0;d<6;d++) v+=sXL[j*6+d]*sEW[d*64+m];
      sHt[m*64+j]=v; sAb[j*136+m]=(__bf16)v; } }
  __syncthreads();

  // G = nw2@fw3 (skewed n to dodge bank conflicts), hf3 = h@fw3, cvec
  if (tid<192){
    int k=tid&63, d=tid>>6;
    float gacc=0.f, s=0.f;
    for (int nn=0;nn<64;nn++){
      int n=(nn+k)&63;
      gacc += sNW2[k*64+n]*sFW3[n*4+d];
      s    += sHt[nn*64+k]*sFW3[nn*4+d];
    }
    sG[k*4+d]=gacc; sHf3[k*4+d]=s;
  } else if (tid<195){
    int d=tid-192; float c=final_b[3+d];
    for (int n=0;n<64;n++) c+=sNB2[n]*sFW3[n*4+d];
    sCvec[d]=c;
  }
  __syncthreads();

  // z GEMM: wave wv owns 16-row j-tile, K=128, N=64
  f32x4 acc[4];
  #pragma unroll
  for (int nt=0;nt<4;nt++) acc[nt]=f32x4{0.f,0.f,0.f,0.f};
  #pragma unroll
  for (int kb=0;kb<4;kb++){
    bf16x8 a8 = *(const bf16x8*)&sAb[(wv*16+ln)*136 + kb*32 + lg*8];
    #pragma unroll
    for (int nt=0;nt<4;nt++){
      bf16x8 b8 = *(const bf16x8*)&sNW1t[(nt*16+ln)*136 + kb*32 + lg*8];
      acc[nt]=mfma16(a8,b8,acc[nt]);
    }
  }
  // vel epilogue: p[r][d] = sum_n relu(z)*G[n][d], butterfly over 16 n-lanes
  float p[4][3];
  #pragma unroll
  for(int r=0;r<4;r++){ p[r][0]=0.f; p[r][1]=0.f; p[r][2]=0.f; }
  #pragma unroll
  for (int nt=0;nt<4;nt++){
    int n=nt*16+ln;
    float zb=sNB1[n];
    float g0=sG[n*4], g1=sG[n*4+1], g2=sG[n*4+2];
    #pragma unroll
    for (int r=0;r<4;r++){
      float u=fmaxf(acc[nt][r]+zb,0.f);
      p[r][0]+=u*g0; p[r][1]+=u*g1; p[r][2]+=u*g2;
    }
  }
  #pragma unroll
  for (int off=1;off<16;off<<=1)
    #pragma unroll
    for (int r=0;r<4;r++){
      p[r][0]+=__shfl_xor(p[r][0],off);
      p[r][1]+=__shfl_xor(p[r][1],off);
      p[r][2]+=__shfl_xor(p[r][2],off);
    }
  if (ln==0){
    #pragma unroll
    for (int r=0;r<4;r++){
      int j=wv*16+lg*4+r; int base=(bs*64+j)*6;
      #pragma unroll
      for (int d=0;d<3;d++)
        out[base+3+d]=xg[j*6+3+d]+sHf3[j*4+d]+sCvec[d]+p[r][d];
    }
  }
}

extern "C" void kernel_launch(void* const* d_in, const int* in_sizes, int n_in,
                              void* d_out, int out_size, void* d_ws, size_t ws_size,
                              hipStream_t stream)
{
  const float* x        = (const float*)d_in[0];
  const float* emb_w    = (const float*)d_in[1];
  const float* emb_b    = (const float*)d_in[2];
  const float* edge_w1  = (const float*)d_in[3];
  const float* edge_b1  = (const float*)d_in[4];
  const float* edge_w2  = (const float*)d_in[5];
  const float* edge_b2  = (const float*)d_in[6];
  const float* node_w1  = (const float*)d_in[7];
  const float* node_b1  = (const float*)d_in[8];
  const float* node_w2  = (const float*)d_in[9];
  const float* node_b2  = (const float*)d_in[10];
  const float* coord_w1 = (const float*)d_in[11];
  const float* coord_b1 = (const float*)d_in[12];
  const float* coord_w2 = (const float*)d_in[13];
  const float* final_w  = (const float*)d_in[14];
  const float* final_b  = (const float*)d_in[15];
  float* out   = (float*)d_out;
  float* ws_mi = (float*)d_ws;   // 256*64*64 f32 = 4 MB

  egnn_edge_mfma<<<NG, 512, 0, stream>>>(x, emb_w, emb_b,
      edge_w1, edge_b1, edge_w2, edge_b2, coord_w1, coord_b1, coord_w2,
      out, ws_mi);
  egnn_node_mfma<<<NG, 256, 0, stream>>>(x, emb_w, emb_b,
      node_w1, node_b1, node_w2, node_b2, final_w, final_b,
      out, ws_mi);
}